// Round 4
// baseline (1312.682 us; speedup 1.0000x reference)
//
#include <hip/hip_runtime.h>
#include <cstdint>
#include <cstddef>

typedef unsigned short u16;

#define HH 256
#define IIN 128
#define TT 512
#define G3 768

typedef __attribute__((ext_vector_type(8))) short bf16x8;
typedef __attribute__((ext_vector_type(4))) float f32x4;

__device__ __forceinline__ u16 f2bf(float f) {
    union { float f; uint32_t i; } c; c.f = f;
    uint32_t r = c.i + 0x7fffu + ((c.i >> 16) & 1u);
    return (u16)(r >> 16);
}
__device__ __forceinline__ float frcp(float x) { return __builtin_amdgcn_rcpf(x); }
__device__ __forceinline__ float sigm(float x) {
    float e = __expf(-fabsf(x));
    float s = frcp(1.f + e);
    return x >= 0.f ? s : 1.f - s;   // 1-s == e/(1+e)
}
__device__ __forceinline__ float tanh_f(float x) {
    float e = __expf(-2.f * fabsf(x));          // overflow-safe
    float t = (1.f - e) * frcp(1.f + e);
    return x >= 0.f ? t : -t;
}

// ---------------------------------------------------------------------------
// Kernel 1: xg[m][g] = x_row(m) . W_ih[g] + b_ih[g] + (g<512 ? b_hh[g] : 0)
// fp32 in -> bf16 LDS staging -> MFMA -> fp32 xg.
// Chunked row map: m = b*Tc + (t-t0), so b = m>>lt, t = t0 + (m & (Tc-1)).
// ---------------------------------------------------------------------------
__global__ __launch_bounds__(256, 2) void xg_gemm(
    const float* __restrict__ x, const float* __restrict__ W_ih,
    const float* __restrict__ b_ih, const float* __restrict__ b_hh,
    float* __restrict__ xg, int t0, int lt)
{
    // stride 136 u16 = 272B (odd multiple of 16B) -> conflict-free b128 reads
    __shared__ u16 xA[128 * 136];
    __shared__ u16 wB[128 * 136];
    __shared__ float biasS[128];
    const int tid = threadIdx.x;
    const int m0 = blockIdx.x * 128;
    const int n0 = blockIdx.y * 128;
    const int TcM = (1 << lt) - 1;

    {   // stage fp32 -> bf16: 8 rows/pass, 4 floats (16B)/thread, 16 passes
        const int srow = tid >> 5, sc = (tid & 31) * 4;
        #pragma unroll
        for (int it = 0; it < 16; ++it) {
            int r = srow + it * 8;
            int row = m0 + r;
            int b = row >> lt;
            int t = t0 + (row & TcM);
            float4 xv = *(const float4*)(x + ((size_t)b * TT + t) * IIN + sc);
            ushort4 xs = { f2bf(xv.x), f2bf(xv.y), f2bf(xv.z), f2bf(xv.w) };
            *(ushort4*)&xA[r * 136 + sc] = xs;
            float4 wv4 = *(const float4*)(W_ih + (size_t)(n0 + r) * IIN + sc);
            ushort4 ws4 = { f2bf(wv4.x), f2bf(wv4.y), f2bf(wv4.z), f2bf(wv4.w) };
            *(ushort4*)&wB[r * 136 + sc] = ws4;
        }
        if (tid < 128) {
            int n = n0 + tid;
            float bv = b_ih[n];
            if (n < 512) bv += b_hh[n];   // fold b_hh into r,z pre-activations
            biasS[tid] = bv;
        }
    }
    __syncthreads();

    const int lane = tid & 63, wv = tid >> 6;
    const int quad = lane >> 4, colL = lane & 15;

    f32x4 C[2][8] = {};
    #pragma unroll
    for (int kt = 0; kt < 4; ++kt) {
        bf16x8 A[2];
        #pragma unroll
        for (int i = 0; i < 2; ++i)
            A[i] = *(const bf16x8*)&xA[(wv * 32 + i * 16 + colL) * 136 + kt * 32 + quad * 8];
        #pragma unroll
        for (int nn = 0; nn < 8; ++nn) {
            bf16x8 Bf = *(const bf16x8*)&wB[(nn * 16 + colL) * 136 + kt * 32 + quad * 8];
            C[0][nn] = __builtin_amdgcn_mfma_f32_16x16x32_bf16(A[0], Bf, C[0][nn], 0, 0, 0);
            C[1][nn] = __builtin_amdgcn_mfma_f32_16x16x32_bf16(A[1], Bf, C[1][nn], 0, 0, 0);
        }
    }
    // C layout [m89]: row = quad*4 + reg, col = lane&15
    #pragma unroll
    for (int i = 0; i < 2; ++i)
        #pragma unroll
        for (int nn = 0; nn < 8; ++nn) {
            int c = nn * 16 + colL;
            float bv = biasS[c];
            #pragma unroll
            for (int r = 0; r < 4; ++r) {
                int row = m0 + wv * 32 + i * 16 + quad * 4 + r;
                xg[(size_t)row * G3 + n0 + c] = C[i][nn][r] + bv;
            }
        }
}

// ---------------------------------------------------------------------------
// Kernel 2: persistent per-batch recurrence. grid=256 (1 WG/CU), block=256.
// W_hh (fp32) -> bf16 MFMA B-fragments in registers (384 VGPR/lane).
// Wave wv owns hidden j in [64wv, 64wv+64) for all three gates.
// h broadcast via A-fragment row 0: only lanes with (lane&15)==0 carry data.
// ---------------------------------------------------------------------------
#define GRU_STEP(TC_, PR_, PZ_, PN_) do {                                      \
    f32x4 C[3][4] = {};                                                        \
    _Pragma("unroll")                                                          \
    for (int kt = 0; kt < 8; ++kt) {                                           \
        bf16x8 A = {};                                                         \
        if (colL == 0)                                                         \
            A = *(const bf16x8*)&hB[kt * 32 + quad * 8];                       \
        _Pragma("unroll")                                                      \
        for (int g = 0; g < 3; ++g)                                            \
            _Pragma("unroll")                                                  \
            for (int i = 0; i < 4; ++i)                                        \
                C[g][i] = __builtin_amdgcn_mfma_f32_16x16x32_bf16(             \
                              A, Bw[g][i][kt], C[g][i], 0, 0, 0);              \
    }                                                                          \
    if (lane < 16) {   /* C row 0 = quad 0, reg 0 -> lanes 0..15 */            \
        _Pragma("unroll")                                                      \
        for (int g = 0; g < 3; ++g)                                            \
            _Pragma("unroll")                                                  \
            for (int i = 0; i < 4; ++i)                                        \
                stg[g][wv * 64 + i * 16 + lane] = C[g][i][0];                  \
    }                                                                          \
    __syncthreads();                                                           \
    float xr = PR_, xz = PZ_, xn = PN_;                                        \
    int t2 = (TC_) + 2; if (t2 > Tc - 1) t2 = Tc - 1;                          \
    const float* p2 = xgb + (size_t)t2 * G3;                                   \
    PR_ = p2[tid]; PZ_ = p2[256 + tid]; PN_ = p2[512 + tid];                   \
    float r = sigm(xr + stg[0][tid]);                                          \
    float z = sigm(xz + stg[1][tid]);                                          \
    float n = tanh_f(xn + r * (stg[2][tid] + bhn));                            \
    float hnew = n + z * (hF[tid] - n);                                        \
    hF[tid] = hnew;                                                            \
    hB[tid] = f2bf(hnew);                                                      \
    outb[(size_t)(t0 + (TC_)) * HH + tid] = hnew;                              \
    __syncthreads();                                                           \
} while (0)

__global__ __launch_bounds__(256, 1) void gru_seq(
    const float* __restrict__ W_hh, const float* __restrict__ b_hh,
    const float* __restrict__ xg, float* __restrict__ out,
    float* __restrict__ hstate, int t0, int Tc)
{
    __shared__ u16 hB[HH];          // h, bf16 (A-fragment source)
    __shared__ float hF[HH];        // h, fp32 carry
    __shared__ float stg[3][HH];    // W_hh.h dot results per gate

    const int tid = threadIdx.x;
    const int lane = tid & 63, wv = tid >> 6;
    const int quad = lane >> 4, colL = lane & 15;
    const int b = blockIdx.x;

    // persistent weight fragments: B[k][n=colL] = W_hh[rowbase+colL][k]
    bf16x8 Bw[3][4][8];
    #pragma unroll
    for (int g = 0; g < 3; ++g)
        #pragma unroll
        for (int i = 0; i < 4; ++i) {
            const size_t rowb = (size_t)(g * 256 + wv * 64 + i * 16 + colL) * HH;
            #pragma unroll
            for (int kt = 0; kt < 8; ++kt) {
                float4 lo = *(const float4*)(W_hh + rowb + kt * 32 + quad * 8);
                float4 hi = *(const float4*)(W_hh + rowb + kt * 32 + quad * 8 + 4);
                union { bf16x8 v; u16 s[8]; } u;
                u.s[0] = f2bf(lo.x); u.s[1] = f2bf(lo.y);
                u.s[2] = f2bf(lo.z); u.s[3] = f2bf(lo.w);
                u.s[4] = f2bf(hi.x); u.s[5] = f2bf(hi.y);
                u.s[6] = f2bf(hi.z); u.s[7] = f2bf(hi.w);
                Bw[g][i][kt] = u.v;
            }
        }

    float h0v = (t0 == 0) ? 0.f : hstate[b * HH + tid];
    hF[tid] = h0v;
    hB[tid] = f2bf(h0v);
    const float bhn = b_hh[512 + tid];
    const float* xgb = xg + (size_t)b * Tc * G3;
    float* outb = out + (size_t)b * TT * HH;

    // 2-deep xg prefetch
    float pr0 = xgb[tid],      pz0 = xgb[256 + tid],      pn0 = xgb[512 + tid];
    float pr1 = xgb[G3 + tid], pz1 = xgb[G3 + 256 + tid], pn1 = xgb[G3 + 512 + tid];
    __syncthreads();

    for (int tc = 0; tc < Tc; tc += 2) {
        GRU_STEP(tc,     pr0, pz0, pn0);
        GRU_STEP(tc + 1, pr1, pz1, pn1);
    }

    if (t0 + Tc < TT)                       // only needed across chunks
        hstate[b * HH + tid] = hF[tid];
}

extern "C" void kernel_launch(void* const* d_in, const int* in_sizes, int n_in,
                              void* d_out, int out_size, void* d_ws, size_t ws_size,
                              hipStream_t stream) {
    const float* x    = (const float*)d_in[0];
    const float* W_ih = (const float*)d_in[1];
    const float* W_hh = (const float*)d_in[2];
    const float* b_ih = (const float*)d_in[3];
    const float* b_hh = (const float*)d_in[4];
    float* out = (float*)d_out;                    // fp32 output [B,T,H]

    float* hstate = (float*)d_ws;                  // 256*256 fp32 = 256 KB
    float* xg = (float*)((char*)d_ws + 262144);    // [256*Tc, 768] fp32
    size_t avail = ws_size > 262144 ? ws_size - 262144 : 0;

    int Tc = TT, lt = 9;                           // shrink chunk to fit ws
    while (Tc > 4 && (size_t)256 * Tc * G3 * 4 > avail) { Tc >>= 1; --lt; }

    for (int t0 = 0; t0 < TT; t0 += Tc) {
        xg_gemm<<<dim3(2 * Tc, G3 / 128), 256, 0, stream>>>(
            x, W_ih, b_ih, b_hh, xg, t0, lt);
        gru_seq<<<dim3(256), 256, 0, stream>>>(
            W_hh, b_hh, xg, out, hstate, t0, Tc);
    }
}

// Round 5
// 1259.041 us; speedup vs baseline: 1.0426x; 1.0426x over previous
//
#include <hip/hip_runtime.h>
#include <cstdint>
#include <cstddef>

typedef unsigned short u16;

#define HH 256
#define IIN 128
#define TT 512
#define G3 768

typedef __attribute__((ext_vector_type(8))) short bf16x8;
typedef __attribute__((ext_vector_type(4))) float f32x4;

__device__ __forceinline__ u16 f2bf(float f) {
    union { float f; uint32_t i; } c; c.f = f;
    uint32_t r = c.i + 0x7fffu + ((c.i >> 16) & 1u);
    return (u16)(r >> 16);
}
__device__ __forceinline__ float frcp(float x) { return __builtin_amdgcn_rcpf(x); }
__device__ __forceinline__ float sigm(float x) {
    float e = __expf(-fabsf(x));
    float s = frcp(1.f + e);
    return x >= 0.f ? s : 1.f - s;   // 1-s == e/(1+e)
}
__device__ __forceinline__ float tanh_f(float x) {
    float e = __expf(-2.f * fabsf(x));          // overflow-safe
    float t = (1.f - e) * frcp(1.f + e);
    return x >= 0.f ? t : -t;
}

// lgkmcnt-only barrier: drains LDS ops for cross-wave visibility but leaves
// global (vmcnt) loads in flight -- avoids the compiler's vmcnt(0) drain at
// __syncthreads that serialized every recurrent step on HBM latency.
#define LDS_BARRIER() asm volatile("s_waitcnt lgkmcnt(0)\n\ts_barrier" ::: "memory")

// ---------------------------------------------------------------------------
// Kernel 1: xg[m][g] = x_row(m) . W_ih[g] + b_ih[g] + (g<512 ? b_hh[g] : 0)
// fp32 in -> bf16 LDS staging -> MFMA -> fp32 xg.
// Each block: one 128-row x-tile x TWO 128-col W-tiles (x staged once).
// Chunked row map: m = b*Tc + (t-t0): b = m>>lt, t = t0 + (m & (Tc-1)).
// ---------------------------------------------------------------------------
__global__ __launch_bounds__(256, 2) void xg_gemm(
    const float* __restrict__ x, const float* __restrict__ W_ih,
    const float* __restrict__ b_ih, const float* __restrict__ b_hh,
    float* __restrict__ xg, int t0, int lt)
{
    // stride 136 u16 = 272B (odd multiple of 16B) -> conflict-free b128 reads
    __shared__ u16 xA[128 * 136];
    __shared__ u16 wB[128 * 136];
    __shared__ float biasS[128];
    const int tid = threadIdx.x;
    const int m0 = blockIdx.x * 128;
    const int TcM = (1 << lt) - 1;
    const int srow = tid >> 5, sc = (tid & 31) * 4;

    // stage x-tile once (fp32 -> bf16): 8 rows/pass, 4 floats/thread, 16 passes
    #pragma unroll
    for (int it = 0; it < 16; ++it) {
        int r = srow + it * 8;
        int row = m0 + r;
        int b = row >> lt;
        int t = t0 + (row & TcM);
        float4 xv = *(const float4*)(x + ((size_t)b * TT + t) * IIN + sc);
        ushort4 xs = { f2bf(xv.x), f2bf(xv.y), f2bf(xv.z), f2bf(xv.w) };
        *(ushort4*)&xA[r * 136 + sc] = xs;
    }

    const int lane = tid & 63, wv = tid >> 6;
    const int quad = lane >> 4, colL = lane & 15;

    #pragma unroll
    for (int nb = 0; nb < 2; ++nb) {
        const int n0 = blockIdx.y * 256 + nb * 128;
        if (nb) __syncthreads();            // all waves done reading wB
        #pragma unroll
        for (int it = 0; it < 16; ++it) {
            int r = srow + it * 8;
            float4 wv4 = *(const float4*)(W_ih + (size_t)(n0 + r) * IIN + sc);
            ushort4 ws4 = { f2bf(wv4.x), f2bf(wv4.y), f2bf(wv4.z), f2bf(wv4.w) };
            *(ushort4*)&wB[r * 136 + sc] = ws4;
        }
        if (tid < 128) {
            int n = n0 + tid;
            float bv = b_ih[n];
            if (n < 512) bv += b_hh[n];     // fold b_hh into r,z pre-activations
            biasS[tid] = bv;
        }
        __syncthreads();

        f32x4 C[2][8] = {};
        #pragma unroll
        for (int kt = 0; kt < 4; ++kt) {
            bf16x8 A[2];
            #pragma unroll
            for (int i = 0; i < 2; ++i)
                A[i] = *(const bf16x8*)&xA[(wv * 32 + i * 16 + colL) * 136 + kt * 32 + quad * 8];
            #pragma unroll
            for (int nn = 0; nn < 8; ++nn) {
                bf16x8 Bf = *(const bf16x8*)&wB[(nn * 16 + colL) * 136 + kt * 32 + quad * 8];
                C[0][nn] = __builtin_amdgcn_mfma_f32_16x16x32_bf16(A[0], Bf, C[0][nn], 0, 0, 0);
                C[1][nn] = __builtin_amdgcn_mfma_f32_16x16x32_bf16(A[1], Bf, C[1][nn], 0, 0, 0);
            }
        }
        // C layout [m89]: row = quad*4 + reg, col = lane&15
        #pragma unroll
        for (int i = 0; i < 2; ++i)
            #pragma unroll
            for (int nn = 0; nn < 8; ++nn) {
                int c = nn * 16 + colL;
                float bv = biasS[c];
                #pragma unroll
                for (int r = 0; r < 4; ++r) {
                    int row = m0 + wv * 32 + i * 16 + quad * 4 + r;
                    xg[(size_t)row * G3 + n0 + c] = C[i][nn][r] + bv;
                }
            }
    }
}

// ---------------------------------------------------------------------------
// Kernel 2: persistent per-batch recurrence. grid=256 (1 WG/CU), block=256.
// W_hh (fp32) -> bf16 MFMA B-fragments in registers. Wave wv owns hidden
// j in [64wv,64wv+64) for all three gates -> stg + gate math are WAVE-LOCAL.
// Only cross-wave data is h: double-buffered in LDS -> ONE lgkmcnt-only
// barrier per step; xg prefetch loads stay in flight across it (consumed
// 2 steps later, so ~900cyc HBM latency is hidden).
// ---------------------------------------------------------------------------
#define GRU_STEP(TC_, HBR_, HBW_, PR_, PZ_, PN_) do {                          \
    f32x4 C[3][4] = {};                                                        \
    _Pragma("unroll")                                                          \
    for (int kt = 0; kt < 8; ++kt) {                                           \
        bf16x8 A = {};                                                         \
        if (colL == 0)                                                         \
            A = *(const bf16x8*)&HBR_[kt * 32 + quad * 8];                     \
        _Pragma("unroll")                                                      \
        for (int g = 0; g < 3; ++g)                                            \
            _Pragma("unroll")                                                  \
            for (int i = 0; i < 4; ++i)                                        \
                C[g][i] = __builtin_amdgcn_mfma_f32_16x16x32_bf16(             \
                              A, Bw[g][i][kt], C[g][i], 0, 0, 0);              \
    }                                                                          \
    if (lane < 16) {   /* C row 0 = quad 0, reg 0 -> lanes 0..15 */            \
        _Pragma("unroll")                                                      \
        for (int g = 0; g < 3; ++g)                                            \
            _Pragma("unroll")                                                  \
            for (int i = 0; i < 4; ++i)                                        \
                stg[g][wv * 64 + i * 16 + lane] = C[g][i][0];                  \
    }                                                                          \
    asm volatile("s_waitcnt lgkmcnt(0)" ::: "memory"); /* wave-local RAW */    \
    float xr = PR_, xz = PZ_, xn = PN_;                                        \
    int t2 = (TC_) + 2; if (t2 > Tc - 1) t2 = Tc - 1;                          \
    const float* p2 = xgb + (size_t)t2 * G3;                                   \
    PR_ = p2[tid]; PZ_ = p2[256 + tid]; PN_ = p2[512 + tid];                   \
    float r = sigm(xr + stg[0][tid]);                                          \
    float z = sigm(xz + stg[1][tid]);                                          \
    float n = tanh_f(xn + r * (stg[2][tid] + bhn));                            \
    hreg = n + z * (hreg - n);                                                 \
    HBW_[tid] = f2bf(hreg);                                                    \
    outb[(size_t)(t0 + (TC_)) * HH + tid] = hreg;                              \
    LDS_BARRIER();                                                             \
} while (0)

__global__ __launch_bounds__(256, 1) void gru_seq(
    const float* __restrict__ W_hh, const float* __restrict__ b_hh,
    const float* __restrict__ xg, float* __restrict__ out,
    float* __restrict__ hstate, int t0, int Tc)
{
    __shared__ u16 hBuf[2][HH];     // h bf16, double-buffered (A-frag source)
    __shared__ float stg[3][HH];    // W_hh.h dots, wave-local slices

    const int tid = threadIdx.x;
    const int lane = tid & 63, wv = tid >> 6;
    const int quad = lane >> 4, colL = lane & 15;
    const int b = blockIdx.x;

    // persistent weight fragments: B[k][n=colL] = W_hh[rowbase+colL][k]
    bf16x8 Bw[3][4][8];
    #pragma unroll
    for (int g = 0; g < 3; ++g)
        #pragma unroll
        for (int i = 0; i < 4; ++i) {
            const size_t rowb = (size_t)(g * 256 + wv * 64 + i * 16 + colL) * HH;
            #pragma unroll
            for (int kt = 0; kt < 8; ++kt) {
                float4 lo = *(const float4*)(W_hh + rowb + kt * 32 + quad * 8);
                float4 hi = *(const float4*)(W_hh + rowb + kt * 32 + quad * 8 + 4);
                union { bf16x8 v; u16 s[8]; } u;
                u.s[0] = f2bf(lo.x); u.s[1] = f2bf(lo.y);
                u.s[2] = f2bf(lo.z); u.s[3] = f2bf(lo.w);
                u.s[4] = f2bf(hi.x); u.s[5] = f2bf(hi.y);
                u.s[6] = f2bf(hi.z); u.s[7] = f2bf(hi.w);
                Bw[g][i][kt] = u.v;
            }
        }

    float hreg = (t0 == 0) ? 0.f : hstate[b * HH + tid];
    hBuf[0][tid] = f2bf(hreg);
    const float bhn = b_hh[512 + tid];
    const float* xgb = xg + (size_t)b * Tc * G3;
    float* outb = out + (size_t)b * TT * HH;

    // 2-deep xg prefetch
    float pr0 = xgb[tid],      pz0 = xgb[256 + tid],      pn0 = xgb[512 + tid];
    float pr1 = xgb[G3 + tid], pz1 = xgb[G3 + 256 + tid], pn1 = xgb[G3 + 512 + tid];
    __syncthreads();   // once: weight/h init visible

    for (int tc = 0; tc < Tc; tc += 2) {
        GRU_STEP(tc,     hBuf[0], hBuf[1], pr0, pz0, pn0);
        GRU_STEP(tc + 1, hBuf[1], hBuf[0], pr1, pz1, pn1);
    }

    if (t0 + Tc < TT)                       // only needed across chunks
        hstate[b * HH + tid] = hreg;
}

extern "C" void kernel_launch(void* const* d_in, const int* in_sizes, int n_in,
                              void* d_out, int out_size, void* d_ws, size_t ws_size,
                              hipStream_t stream) {
    const float* x    = (const float*)d_in[0];
    const float* W_ih = (const float*)d_in[1];
    const float* W_hh = (const float*)d_in[2];
    const float* b_ih = (const float*)d_in[3];
    const float* b_hh = (const float*)d_in[4];
    float* out = (float*)d_out;                    // fp32 output [B,T,H]

    float* hstate = (float*)d_ws;                  // 256*256 fp32 = 256 KB
    float* xg = (float*)((char*)d_ws + 262144);    // [256*Tc, 768] fp32
    size_t avail = ws_size > 262144 ? ws_size - 262144 : 0;

    int Tc = TT, lt = 9;                           // shrink chunk to fit ws
    while (Tc > 4 && (size_t)256 * Tc * G3 * 4 > avail) { Tc >>= 1; --lt; }

    for (int t0 = 0; t0 < TT; t0 += Tc) {
        xg_gemm<<<dim3(2 * Tc, G3 / 256), 256, 0, stream>>>(
            x, W_ih, b_ih, b_hh, xg, t0, lt);
        gru_seq<<<dim3(256), 256, 0, stream>>>(
            W_hh, b_hh, xg, out, hstate, t0, Tc);
    }
}